// Round 5
// baseline (277.641 us; speedup 1.0000x reference)
//
#include <hip/hip_runtime.h>
#include <math.h>

// FreqEmbedding: seq [16,512,64] f32 -> out [16,512,65,64] f32
// reflect-pad(64) -> hanning(128) frames -> rfft(128) -> complex standardize
// over (L,F) per (B,C) -> abs.
//
// Pass A (reduce): NO FFT — Parseval + symmetry identities (4 dot products).
// Pass B (write): lane-pair split FFT. Lane pair (i, i^32) shares one (b,l,c)
//   frame: lam=0 does 32-pt FFT of even c64 samples (E), lam=1 of odd (O).
//   One shfl_xor(32) exchange forms Z[k]=E+W64^k*O (lam0) / Z[64-k] (lam1);
//   a second streamed exchange does the real-FFT unpack per bin.
//   State = 32 float2 = 64 VGPR -> target 4 waves/SIMD (was 2 with 128-f32).

#define B_ 16
#define L_ 512
#define C_ 64
#define W_ 128
#define F_ 65
#define NLF (L_ * F_)  // 33280

// ---------- compile-time trig tables (fold to VALU literals) ----------
constexpr double kPI = 3.14159265358979323846;

constexpr double csin_(double x) {
  while (x > kPI) x -= 2.0 * kPI;
  while (x < -kPI) x += 2.0 * kPI;
  double t = x, s = x, x2 = x * x;
  for (int i = 1; i <= 24; ++i) {
    t *= -x2 / ((2.0 * i) * (2.0 * i + 1.0));
    s += t;
  }
  return s;
}
constexpr double ccos_(double x) { return csin_(kPI / 2.0 - x); }

constexpr int bitrev5(int n) {
  int r = 0;
  for (int i = 0; i < 5; ++i) r |= ((n >> i) & 1) << (4 - i);
  return r;
}

struct Tables {
  float win[128];         // hanning w_n
  float walt[128];        // (-1)^n w_n
  float w2[128];          // w_n^2
  float wg[128];          // w_n * G_n
  float t32r[16], t32i[16]; // exp(-2*pi*i*r/32)
  float twr[32], twi[32];   // exp(-2*pi*i*k/64)
  float cur[32], cui[32];   // exp(-2*pi*i*k/128)
  constexpr Tables()
      : win(), walt(), w2(), wg(), t32r(), t32i(), twr(), twi(), cur(), cui() {
    for (int n = 0; n < 128; ++n) {
      const double wd = 0.5 - 0.5 * ccos_(2.0 * kPI * n / 127.0);
      win[n] = (float)wd;
      walt[n] = (n & 1) ? (float)(-wd) : (float)wd;
      w2[n] = (float)(wd * wd);
      if (n == 0) {
        wg[n] = 0.0f;
      } else {
        const double G = csin_(kPI * n / 2.0) * csin_(65.0 * kPI * n / 128.0) /
                         csin_(kPI * n / 128.0);
        wg[n] = (float)(wd * G);
      }
    }
    for (int r = 0; r < 16; ++r) {
      t32r[r] = (float)ccos_(2.0 * kPI * r / 32.0);
      t32i[r] = (float)(-csin_(2.0 * kPI * r / 32.0));
    }
    for (int j = 0; j < 32; ++j) {
      twr[j] = (float)ccos_(2.0 * kPI * j / 64.0);
      twi[j] = (float)(-csin_(2.0 * kPI * j / 64.0));
    }
    for (int k = 0; k < 32; ++k) {
      cur[k] = (float)ccos_(2.0 * kPI * k / 128.0);
      cui[k] = (float)(-csin_(2.0 * kPI * k / 128.0));
    }
  }
};
constexpr Tables TBL{};

// reflect index into [0, 512)
__device__ __forceinline__ int refl(int t) {
  t = t < 0 ? -t : t;
  return t >= L_ ? (2 * (L_ - 1) - t) : t;
}

__device__ __forceinline__ float fast_sqrt(float x) {
  float r;
  asm("v_sqrt_f32 %0, %1" : "=v"(r) : "v"(x));
  return r;
}

struct cplx { float x, y; };

// ---------------- Pass A: Parseval reduce (unchanged) ----------------
__global__ void __launch_bounds__(256)
fe_reduce_kernel(const float* __restrict__ seq, float* __restrict__ acc) {
  const int p = blockIdx.x * 4 + (threadIdx.x >> 6);
  const int b = __builtin_amdgcn_readfirstlane(p >> 9);
  const int l = __builtin_amdgcn_readfirstlane(p & (L_ - 1));
  const int c = threadIdx.x & 63;

  const float* base = seq + ((size_t)b * L_) * C_ + c;

  float x0 = 0.f, x64 = 0.f, p2 = 0.f, d2 = 0.f;
#pragma unroll
  for (int n = 0; n < 128; ++n) {
    const int t = refl(l + n - 64);
    const float v = base[(size_t)t * C_];
    x0 += TBL.win[n] * v;
    x64 += TBL.walt[n] * v;
    const float wv = TBL.w2[n] * v;
    p2 += wv * v;
    d2 += TBL.wg[n] * v;
  }

  const float sre = 0.5f * (x0 + x64);
  const float sim = -d2;
  const float ssq = 64.0f * p2 + 0.5f * (x0 * x0 + x64 * x64);

  __shared__ float red[3][256];
  const int tid = threadIdx.x;
  red[0][tid] = sre;
  red[1][tid] = sim;
  red[2][tid] = ssq;
  __syncthreads();
  if (tid < 64) {
    const float a0 = red[0][tid] + red[0][tid + 64] + red[0][tid + 128] + red[0][tid + 192];
    const float a1 = red[1][tid] + red[1][tid + 64] + red[1][tid + 128] + red[1][tid + 192];
    const float a2 = red[2][tid] + red[2][tid + 64] + red[2][tid + 128] + red[2][tid + 192];
    const int g = b * C_ + tid;
    unsafeAtomicAdd(&acc[g], a0);
    unsafeAtomicAdd(&acc[1024 + g], a1);
    unsafeAtomicAdd(&acc[2048 + g], a2);
  }
}

// ---------------- Pass B: lane-pair split FFT + write ----------------
template <bool FAST>
__device__ __forceinline__ void fe_write_body(
    const float* __restrict__ pbc,  // FAST: seq+bLC+(l-64)C+c ; else seq+bLC+c
    float* __restrict__ out, int ob, int l, int lam,
    float mr, float mi, float is) {
  cplx z[32];

  // ---- load: lam0 takes c64 even samples (n=4j,4j+1), lam1 odd (4j+2,4j+3),
  //      in bit-reversed-j order, window applied ----
  const int lamo = lam << 7;  // lam * 2 samples * C_ elements
#pragma unroll
  for (int j = 0; j < 32; ++j) {
    const int b4 = 4 * bitrev5(j);
    const float wA = lam ? TBL.win[b4 + 2] : TBL.win[b4];
    const float wB = lam ? TBL.win[b4 + 3] : TBL.win[b4 + 1];
    int off0, off1;
    if (FAST) {
      off0 = b4 * C_ + lamo;
      off1 = off0 + C_;
    } else {
      const int t0 = refl(l - 64 + b4), t1 = refl(l - 64 + b4 + 1);
      const int t2 = refl(l - 64 + b4 + 2), t3 = refl(l - 64 + b4 + 3);
      off0 = (lam ? t2 : t0) * C_;
      off1 = (lam ? t3 : t1) * C_;
    }
    z[j].x = wA * pbc[off0];
    z[j].y = wB * pbc[off1];
  }

  // ---- 32-pt complex DIT FFT (fully unrolled, literal twiddles) ----
#pragma unroll
  for (int s = 0; s < 5; ++s) {
    const int half = 1 << s;
    const int len = half << 1;
#pragma unroll
    for (int j = 0; j < half; ++j) {
      const float wr = TBL.t32r[j << (4 - s)];
      const float wi = TBL.t32i[j << (4 - s)];
#pragma unroll
      for (int base = 0; base < 32; base += len) {
        const int a = base + j;
        const int b2 = a + half;
        const float tr = wr * z[b2].x - wi * z[b2].y;
        const float ti = wr * z[b2].y + wi * z[b2].x;
        z[b2].x = z[a].x - tr;
        z[b2].y = z[a].y - ti;
        z[a].x += tr;
        z[a].y += ti;
      }
    }
  }

  // ---- combine across lane pair: lam0 ends with Z[k] (k=0..31),
  //      lam1 with Z[64-k] in slot k (slot0 = Z[32]) ----
#pragma unroll
  for (int k = 0; k <= 16; ++k) {
    const int m = (32 - k) & 31;
    const float vkx = lam ? (TBL.twr[k] * z[k].x - TBL.twi[k] * z[k].y) : z[k].x;
    const float vky = lam ? (TBL.twr[k] * z[k].y + TBL.twi[k] * z[k].x) : z[k].y;
    const float okx = __shfl_xor(vkx, 32, 64);
    const float oky = __shfl_xor(vky, 32, 64);
    if (k == 0 || k == 16) {
      z[k].x = lam ? (okx - vkx) : (vkx + okx);
      z[k].y = lam ? (oky - vky) : (vky + oky);
    } else {
      const float vmx = lam ? (TBL.twr[m] * z[m].x - TBL.twi[m] * z[m].y) : z[m].x;
      const float vmy = lam ? (TBL.twr[m] * z[m].y + TBL.twi[m] * z[m].x) : z[m].y;
      const float omx = __shfl_xor(vmx, 32, 64);
      const float omy = __shfl_xor(vmy, 32, 64);
      z[k].x = lam ? (omx - vmx) : (vkx + okx);
      z[k].y = lam ? (omy - vmy) : (vky + oky);
      z[m].x = lam ? (okx - vkx) : (vmx + omx);
      z[m].y = lam ? (oky - vky) : (vmy + omy);
    }
  }

  // ---- epilogue helper ----
  auto emit = [&](int fo, float Xr, float Xi) {
    const float dr = Xr - mr;
    const float di = Xi - mi;
    const float amp = fast_sqrt(__builtin_fmaf(dr, dr, di * di)) * is;
    __builtin_nontemporal_store(amp, out + ob + fo);
  };

  // ---- bins 0, 32, 64 (slot 0 exchange) ----
  {
    const float ax = z[0].x, ay = z[0].y;
    const float ox = __shfl_xor(ax, 32, 64);
    const float oy = __shfl_xor(ay, 32, 64);
    if (!lam) {
      emit(0, 2.0f * (ax + ay), 0.0f);              // X[0]   (own Z[0])
      emit(32 * C_, 2.0f * ox, -2.0f * oy);         // X[32]  (recv Z[32])
    } else {
      emit(64 * C_, 2.0f * (ox - oy), 0.0f);        // X[64]  (recv Z[0])
    }
  }

  // ---- bins k / 64-k, streamed exchange + unpack ----
#pragma unroll
  for (int k = 1; k < 32; ++k) {
    const float axv = z[k].x, ayv = z[k].y;      // lam0: Z[k], lam1: Z[64-k]
    const float oxv = __shfl_xor(axv, 32, 64);
    const float oyv = __shfl_xor(ayv, 32, 64);
    const float Zkr = lam ? oxv : axv;
    const float Zki = lam ? oyv : ayv;
    const float Z6r = lam ? axv : oxv;
    const float Z6i = lam ? ayv : oyv;
    const float Er = Zkr + Z6r;
    const float Ei = Zki - Z6i;
    const float Or = Zki + Z6i;
    const float Oi = Z6r - Zkr;
    const float wOr = TBL.cur[k] * Or - TBL.cui[k] * Oi;
    const float wOi = TBL.cur[k] * Oi + TBL.cui[k] * Or;
    const float Xr = lam ? (Er - wOr) : (Er + wOr);
    const float Xi = lam ? (wOi - Ei) : (Ei + wOi);
    const int fo = (k + lam * (64 - 2 * k)) * C_;  // f = k or 64-k
    emit(fo, Xr, Xi);
  }
}

__global__ void __launch_bounds__(256, 4)
fe_write_kernel(const float* __restrict__ seq, const float* __restrict__ acc,
                float* __restrict__ out) {
  const int tid = threadIdx.x;
  const int lam = (tid >> 5) & 1;
  const int c = (tid & 31) | (((tid >> 6) & 1) << 5);
  const int b = __builtin_amdgcn_readfirstlane(blockIdx.x >> 8);
  const int l = __builtin_amdgcn_readfirstlane(((blockIdx.x & 255) << 1) | (tid >> 7));

  // fused finalize: true-scale sums -> constants matching the 2x bins
  const int g = b * C_ + c;
  const float invN = 1.0f / (float)NLF;
  const float sr = acc[g] * invN;
  const float si = acc[1024 + g] * invN;
  const float qq = acc[2048 + g] * invN;
  const float var = qq - sr * sr - si * si;
  const float mr = 2.0f * sr;
  const float mi = 2.0f * si;
  const float is = 0.5f * rsqrtf(var);

  const int ob = ((b * L_ + l) * F_) * C_ + c;

  if (l >= 64 && l <= 448) {
    const float* pbc = seq + (size_t)b * L_ * C_ + (l - 64) * C_ + c;
    fe_write_body<true>(pbc, out, ob, l, lam, mr, mi, is);
  } else {
    const float* pbc = seq + (size_t)b * L_ * C_ + c;
    fe_write_body<false>(pbc, out, ob, l, lam, mr, mi, is);
  }
}

extern "C" void kernel_launch(void* const* d_in, const int* in_sizes, int n_in,
                              void* d_out, int out_size, void* d_ws, size_t ws_size,
                              hipStream_t stream) {
  const float* seq = (const float*)d_in[0];
  float* out = (float*)d_out;
  float* ws = (float*)d_ws;

  // zero the 3 accumulator arrays (3072 floats)
  hipMemsetAsync(ws, 0, 3072 * sizeof(float), stream);

  fe_reduce_kernel<<<(B_ * L_) / 4, 256, 0, stream>>>(seq, ws);
  // 2 (b,l) frames per block, 2 lanes per frame-channel
  fe_write_kernel<<<B_ * L_ / 2, 256, 0, stream>>>(seq, ws, out);
}

// Round 6
// 87.827 us; speedup vs baseline: 3.1612x; 3.1612x over previous
//
#include <hip/hip_runtime.h>
#include <math.h>

// FreqEmbedding: seq [16,512,64] f32 -> out [16,512,65,64] f32
// reflect-pad(64) -> hanning(128) frames -> rfft(128) -> complex standardize
// over (L,F) per (B,C) -> abs.
//
// Pass A (reduce): NO FFT — Parseval + symmetry identities (4 dot products).
// Pass B (write): lane-pair split FFT, SINGLE fused exchange+unpack pass.
//   Lane pair (i, i^32) shares one (b,l,c) frame: lam=0 holds E=FFT32(even
//   packed samples), lam=1 holds O=FFT32(odd). Per k: one 4-shfl exchange
//   gives both lanes {E,O}[k],[32-k]; each builds Z[k],Z[32+k],Z[32-k],
//   Z[64-k] locally and emits 2 bins. z[] is read-only after the FFT ->
//   ~100 VGPR peak. launch_bounds(256,3): the one bound that empirically
//   avoids scratch spill (round-5 lesson: (256,4) => 64 VGPR + 881MB spill).

#define B_ 16
#define L_ 512
#define C_ 64
#define W_ 128
#define F_ 65
#define NLF (L_ * F_)  // 33280

// ---------- compile-time trig tables (fold to VALU literals) ----------
constexpr double kPI = 3.14159265358979323846;

constexpr double csin_(double x) {
  while (x > kPI) x -= 2.0 * kPI;
  while (x < -kPI) x += 2.0 * kPI;
  double t = x, s = x, x2 = x * x;
  for (int i = 1; i <= 24; ++i) {
    t *= -x2 / ((2.0 * i) * (2.0 * i + 1.0));
    s += t;
  }
  return s;
}
constexpr double ccos_(double x) { return csin_(kPI / 2.0 - x); }

constexpr int bitrev5(int n) {
  int r = 0;
  for (int i = 0; i < 5; ++i) r |= ((n >> i) & 1) << (4 - i);
  return r;
}

struct Tables {
  float win[128];           // hanning w_n
  float walt[128];          // (-1)^n w_n
  float w2[128];            // w_n^2
  float wg[128];            // w_n * G_n
  float t32r[16], t32i[16]; // exp(-2*pi*i*r/32)
  float twr[32], twi[32];   // exp(-2*pi*i*k/64)
  float cur[32], cui[32];   // exp(-2*pi*i*k/128)
  constexpr Tables()
      : win(), walt(), w2(), wg(), t32r(), t32i(), twr(), twi(), cur(), cui() {
    for (int n = 0; n < 128; ++n) {
      const double wd = 0.5 - 0.5 * ccos_(2.0 * kPI * n / 127.0);
      win[n] = (float)wd;
      walt[n] = (n & 1) ? (float)(-wd) : (float)wd;
      w2[n] = (float)(wd * wd);
      if (n == 0) {
        wg[n] = 0.0f;
      } else {
        const double G = csin_(kPI * n / 2.0) * csin_(65.0 * kPI * n / 128.0) /
                         csin_(kPI * n / 128.0);
        wg[n] = (float)(wd * G);
      }
    }
    for (int r = 0; r < 16; ++r) {
      t32r[r] = (float)ccos_(2.0 * kPI * r / 32.0);
      t32i[r] = (float)(-csin_(2.0 * kPI * r / 32.0));
    }
    for (int j = 0; j < 32; ++j) {
      twr[j] = (float)ccos_(2.0 * kPI * j / 64.0);
      twi[j] = (float)(-csin_(2.0 * kPI * j / 64.0));
    }
    for (int k = 0; k < 32; ++k) {
      cur[k] = (float)ccos_(2.0 * kPI * k / 128.0);
      cui[k] = (float)(-csin_(2.0 * kPI * k / 128.0));
    }
  }
};
constexpr Tables TBL{};

// reflect index into [0, 512)
__device__ __forceinline__ int refl(int t) {
  t = t < 0 ? -t : t;
  return t >= L_ ? (2 * (L_ - 1) - t) : t;
}

__device__ __forceinline__ float fast_sqrt(float x) {
  float r;
  asm("v_sqrt_f32 %0, %1" : "=v"(r) : "v"(x));
  return r;
}

// ---------------- Pass A: Parseval reduce (unchanged) ----------------
__global__ void __launch_bounds__(256)
fe_reduce_kernel(const float* __restrict__ seq, float* __restrict__ acc) {
  const int p = blockIdx.x * 4 + (threadIdx.x >> 6);
  const int b = __builtin_amdgcn_readfirstlane(p >> 9);
  const int l = __builtin_amdgcn_readfirstlane(p & (L_ - 1));
  const int c = threadIdx.x & 63;

  const float* base = seq + ((size_t)b * L_) * C_ + c;

  float x0 = 0.f, x64 = 0.f, p2 = 0.f, d2 = 0.f;
#pragma unroll
  for (int n = 0; n < 128; ++n) {
    const int t = refl(l + n - 64);
    const float v = base[(size_t)t * C_];
    x0 += TBL.win[n] * v;
    x64 += TBL.walt[n] * v;
    const float wv = TBL.w2[n] * v;
    p2 += wv * v;
    d2 += TBL.wg[n] * v;
  }

  const float sre = 0.5f * (x0 + x64);
  const float sim = -d2;
  const float ssq = 64.0f * p2 + 0.5f * (x0 * x0 + x64 * x64);

  __shared__ float red[3][256];
  const int tid = threadIdx.x;
  red[0][tid] = sre;
  red[1][tid] = sim;
  red[2][tid] = ssq;
  __syncthreads();
  if (tid < 64) {
    const float a0 = red[0][tid] + red[0][tid + 64] + red[0][tid + 128] + red[0][tid + 192];
    const float a1 = red[1][tid] + red[1][tid + 64] + red[1][tid + 128] + red[1][tid + 192];
    const float a2 = red[2][tid] + red[2][tid + 64] + red[2][tid + 128] + red[2][tid + 192];
    const int g = b * C_ + tid;
    unsafeAtomicAdd(&acc[g], a0);
    unsafeAtomicAdd(&acc[1024 + g], a1);
    unsafeAtomicAdd(&acc[2048 + g], a2);
  }
}

// ---------------- Pass B: lane-pair split FFT + fused unpack ----------------
template <bool FAST>
__device__ __forceinline__ void fe_write_body(
    const float* __restrict__ pbc,  // FAST: seq+bLC+(l-64)C+c ; else seq+bLC+c
    float* __restrict__ out, int ob, int l, int lam,
    float mr, float mi, float is) {
  float zx[32], zy[32];

  // ---- load: lam0 takes c64 even samples (n=4j,4j+1), lam1 odd (4j+2,4j+3),
  //      in bit-reversed-j order, window applied ----
  const int lamo = lam << 7;  // lam * 2 samples * C_
#pragma unroll
  for (int j = 0; j < 32; ++j) {
    const int b4 = 4 * bitrev5(j);
    const float wA = lam ? TBL.win[b4 + 2] : TBL.win[b4];
    const float wB = lam ? TBL.win[b4 + 3] : TBL.win[b4 + 1];
    int off0, off1;
    if (FAST) {
      off0 = b4 * C_ + lamo;
      off1 = off0 + C_;
    } else {
      const int t0 = refl(l - 64 + b4), t1 = refl(l - 64 + b4 + 1);
      const int t2 = refl(l - 64 + b4 + 2), t3 = refl(l - 64 + b4 + 3);
      off0 = (lam ? t2 : t0) * C_;
      off1 = (lam ? t3 : t1) * C_;
    }
    zx[j] = wA * pbc[off0];
    zy[j] = wB * pbc[off1];
  }

  // ---- 32-pt complex DIT FFT (fully unrolled, literal twiddles) ----
#pragma unroll
  for (int s = 0; s < 5; ++s) {
    const int half = 1 << s;
    const int len = half << 1;
#pragma unroll
    for (int j = 0; j < half; ++j) {
      const float wr = TBL.t32r[j << (4 - s)];
      const float wi = TBL.t32i[j << (4 - s)];
#pragma unroll
      for (int base = 0; base < 32; base += len) {
        const int a = base + j;
        const int b2 = a + half;
        const float tr = wr * zx[b2] - wi * zy[b2];
        const float ti = wr * zy[b2] + wi * zx[b2];
        zx[b2] = zx[a] - tr;
        zy[b2] = zy[a] - ti;
        zx[a] += tr;
        zy[a] += ti;
      }
    }
  }
  // lam0 holds E[0..31], lam1 holds O[0..31]; z is READ-ONLY from here.

  auto emit = [&](int f, float Xr, float Xi) {
    const float dr = Xr - mr;
    const float di = Xi - mi;
    const float amp = fast_sqrt(__builtin_fmaf(dr, dr, di * di)) * is;
    __builtin_nontemporal_store(amp, out + ob + f * C_);
  };

  // ---- k = 0: bins 0, 32, 64 from Z[0]=E0+O0, Z[32]=E0-O0 ----
  {
    const float ox = __shfl_xor(zx[0], 32, 64);
    const float oy = __shfl_xor(zy[0], 32, 64);
    const float E0r = lam ? ox : zx[0], E0i = lam ? oy : zy[0];
    const float O0r = lam ? zx[0] : ox, O0i = lam ? zy[0] : oy;
    if (!lam) {
      emit(0, 2.0f * ((E0r + O0r) + (E0i + O0i)), 0.0f);
      emit(32, 2.0f * (E0r - O0r), -2.0f * (E0i - O0i));
    } else {
      emit(64, 2.0f * ((E0r + O0r) - (E0i + O0i)), 0.0f);
    }
  }

  // ---- k = 16: bins 16, 48 from Z[16]=E16+W^16*O16, Z[48]=E16-W^16*O16 ----
  {
    const float ox = __shfl_xor(zx[16], 32, 64);
    const float oy = __shfl_xor(zy[16], 32, 64);
    const float Egr = lam ? ox : zx[16], Egi = lam ? oy : zy[16];
    const float Ogr = lam ? zx[16] : ox, Ogi = lam ? zy[16] : oy;
    const float ar = TBL.twr[16] * Ogr - TBL.twi[16] * Ogi;
    const float ai = TBL.twr[16] * Ogi + TBL.twi[16] * Ogr;
    const float Zkr = Egr + ar, Zki = Egi + ai;  // Z[16]
    const float Zmr = Egr - ar, Zmi = Egi - ai;  // Z[48]
    const float Er = Zkr + Zmr, Ei = Zki - Zmi;
    const float Or2 = Zki + Zmi, Oi2 = Zmr - Zkr;
    const float wOr = TBL.cur[16] * Or2 - TBL.cui[16] * Oi2;
    const float wOi = TBL.cur[16] * Oi2 + TBL.cui[16] * Or2;
    if (!lam) emit(16, Er + wOr, Ei + wOi);
    else      emit(48, Er - wOr, wOi - Ei);
  }

  // ---- k = 1..15: bins {k, 64-k, 32-k, 32+k} per iteration ----
#pragma unroll
  for (int k = 1; k < 16; ++k) {
    const int m = 32 - k;
    const float okx = __shfl_xor(zx[k], 32, 64);
    const float oky = __shfl_xor(zy[k], 32, 64);
    const float omx = __shfl_xor(zx[m], 32, 64);
    const float omy = __shfl_xor(zy[m], 32, 64);
    const float Ekr = lam ? okx : zx[k], Eki = lam ? oky : zy[k];
    const float Okr = lam ? zx[k] : okx, Oki = lam ? zy[k] : oky;
    const float Emr = lam ? omx : zx[m], Emi = lam ? omy : zy[m];
    const float Omr = lam ? zx[m] : omx, Omi = lam ? zy[m] : omy;
    // a = W64^k * O[k];  bm = W64^m * O[m]
    const float akr = TBL.twr[k] * Okr - TBL.twi[k] * Oki;
    const float aki = TBL.twr[k] * Oki + TBL.twi[k] * Okr;
    const float bmr = TBL.twr[m] * Omr - TBL.twi[m] * Omi;
    const float bmi = TBL.twr[m] * Omi + TBL.twi[m] * Omr;
    const float Zk_r = Ekr + akr, Zk_i = Eki + aki;    // Z[k]
    const float Zkp_r = Ekr - akr, Zkp_i = Eki - aki;  // Z[32+k]
    const float Zm_r = Emr + bmr, Zm_i = Emi + bmi;    // Z[32-k]
    const float Zn_r = Emr - bmr, Zn_i = Emi - bmi;    // Z[64-k]
    // pair (k, 64-k)
    {
      const float Er = Zk_r + Zn_r, Ei = Zk_i - Zn_i;
      const float Or2 = Zk_i + Zn_i, Oi2 = Zn_r - Zk_r;
      const float wOr = TBL.cur[k] * Or2 - TBL.cui[k] * Oi2;
      const float wOi = TBL.cur[k] * Oi2 + TBL.cui[k] * Or2;
      if (!lam) emit(k, Er + wOr, Ei + wOi);
      else      emit(64 - k, Er - wOr, wOi - Ei);
    }
    // pair (32-k, 32+k)
    {
      const float Er = Zm_r + Zkp_r, Ei = Zm_i - Zkp_i;
      const float Or2 = Zm_i + Zkp_i, Oi2 = Zkp_r - Zm_r;
      const float wOr = TBL.cur[m] * Or2 - TBL.cui[m] * Oi2;
      const float wOi = TBL.cur[m] * Oi2 + TBL.cui[m] * Or2;
      if (!lam) emit(m, Er + wOr, Ei + wOi);
      else      emit(32 + k, Er - wOr, wOi - Ei);
    }
  }
}

__global__ void __launch_bounds__(256, 3)
fe_write_kernel(const float* __restrict__ seq, const float* __restrict__ acc,
                float* __restrict__ out) {
  const int tid = threadIdx.x;
  const int lam = (tid >> 5) & 1;
  const int c = (tid & 31) | (((tid >> 6) & 1) << 5);
  const int b = __builtin_amdgcn_readfirstlane(blockIdx.x >> 8);
  const int l = __builtin_amdgcn_readfirstlane(((blockIdx.x & 255) << 1) | (tid >> 7));

  // fused finalize: true-scale sums -> constants matching the 2x bins
  const int g = b * C_ + c;
  const float invN = 1.0f / (float)NLF;
  const float sr = acc[g] * invN;
  const float si = acc[1024 + g] * invN;
  const float qq = acc[2048 + g] * invN;
  const float var = qq - sr * sr - si * si;
  const float mr = 2.0f * sr;
  const float mi = 2.0f * si;
  const float is = 0.5f * rsqrtf(var);

  const int ob = ((b * L_ + l) * F_) * C_ + c;

  if (l >= 64 && l <= 448) {
    const float* pbc = seq + (size_t)b * L_ * C_ + (l - 64) * C_ + c;
    fe_write_body<true>(pbc, out, ob, l, lam, mr, mi, is);
  } else {
    const float* pbc = seq + (size_t)b * L_ * C_ + c;
    fe_write_body<false>(pbc, out, ob, l, lam, mr, mi, is);
  }
}

extern "C" void kernel_launch(void* const* d_in, const int* in_sizes, int n_in,
                              void* d_out, int out_size, void* d_ws, size_t ws_size,
                              hipStream_t stream) {
  const float* seq = (const float*)d_in[0];
  float* out = (float*)d_out;
  float* ws = (float*)d_ws;

  // zero the 3 accumulator arrays (3072 floats)
  hipMemsetAsync(ws, 0, 3072 * sizeof(float), stream);

  fe_reduce_kernel<<<(B_ * L_) / 4, 256, 0, stream>>>(seq, ws);
  // 2 (b,l) frames per block, 2 lane-pairs per frame-channel
  fe_write_kernel<<<B_ * L_ / 2, 256, 0, stream>>>(seq, ws, out);
}